// Round 9
// baseline (984.516 us; speedup 1.0000x reference)
//
#include <hip/hip_runtime.h>
#include <stdint.h>

#define BATCH 4
#define NPTS 4096
#define KNN 11            // K+1 neighbors including self
#define LPQ 16            // lanes per query
#define QPB 16            // queries per block
#define NC 8              // grid cells per axis
#define NCELL (NC*NC*NC)  // 512
#define GMIN (-5.0f)
#define INV_CSZ 0.8f      // 1/1.25
#define SENTINEL_BITS 0x433FFFFFFFFFFFFFll

// ws layout (bytes): sorted float4 | orig idx | cell_start | aabb
#define WS_SRT 0
#define WS_OID 262144
#define WS_CST 327680
#define WS_AAB 335904

// monotone float <-> uint (ascending order preserved)
__device__ __forceinline__ unsigned sortable_f32(float d) {
    unsigned b = __float_as_uint(d);
    unsigned m = (unsigned)(((int)b) >> 31) | 0x80000000u;
    return b ^ m;
}
__device__ __forceinline__ float unsortable_f32(unsigned u) {
    unsigned b = (u & 0x80000000u) ? (u ^ 0x80000000u) : ~u;
    return __uint_as_float(b);
}
__device__ __forceinline__ int cell_of(float v) {
    int c = (int)floorf((v - GMIN) * INV_CSZ);
    return c < 0 ? 0 : (c > NC-1 ? NC-1 : c);
}

// ---------------- build: counting-sort by cell + per-cell AABB ----------------
// One block per batch. Clamped outliers land in edge cells; AABBs are from
// ACTUAL coordinates, so pruning stays conservative regardless of clamping.
__global__ __launch_bounds__(512) void build_kernel(
    const float* __restrict__ pos, float4* __restrict__ srt,
    unsigned* __restrict__ oid, unsigned* __restrict__ cst,
    float* __restrict__ aabb)
{
#pragma clang fp contract(off)
    __shared__ unsigned hist[NCELL];
    __shared__ unsigned scanB[NCELL];
    __shared__ unsigned cursor[NCELL];
    __shared__ unsigned amin[NCELL*3], amax[NCELL*3];

    int b = blockIdx.x;
    int tid = threadIdx.x;
    const float* pb = pos + (size_t)b * NPTS * 3;

    if (tid < NCELL) {
        hist[tid] = 0;
#pragma unroll
        for (int d = 0; d < 3; ++d) { amin[tid*3+d] = 0xFFFFFFFFu; amax[tid*3+d] = 0u; }
    }
    __syncthreads();

    float px[8], py[8], pz[8]; int pc[8];
#pragma unroll
    for (int u = 0; u < 8; ++u) {
        int j = tid + u * 512;
        float x = pb[3*j], y = pb[3*j+1], z = pb[3*j+2];
        px[u] = x; py[u] = y; pz[u] = z;
        int cid = (cell_of(z)*NC + cell_of(y))*NC + cell_of(x);
        pc[u] = cid;
        atomicAdd(&hist[cid], 1u);
        atomicMin(&amin[cid*3+0], sortable_f32(x));
        atomicMin(&amin[cid*3+1], sortable_f32(y));
        atomicMin(&amin[cid*3+2], sortable_f32(z));
        atomicMax(&amax[cid*3+0], sortable_f32(x));
        atomicMax(&amax[cid*3+1], sortable_f32(y));
        atomicMax(&amax[cid*3+2], sortable_f32(z));
    }
    __syncthreads();

    // inclusive Hillis-Steele scan of hist (512 threads == NCELL)
    if (tid < NCELL) scanB[tid] = hist[tid];
    __syncthreads();
    for (int off = 1; off < NCELL; off <<= 1) {
        unsigned add = 0;
        if (tid < NCELL && tid >= off) add = scanB[tid - off];
        __syncthreads();
        if (tid < NCELL) scanB[tid] += add;
        __syncthreads();
    }
    if (tid < NCELL) cursor[tid] = scanB[tid] - hist[tid];   // exclusive start
    __syncthreads();
    if (tid < NCELL) cst[(size_t)b*(NCELL+1) + tid] = cursor[tid];
    if (tid == 0)    cst[(size_t)b*(NCELL+1) + NCELL] = NPTS;
    __syncthreads();                      // cst committed before cursor mutates

#pragma unroll
    for (int u = 0; u < 8; ++u) {
        int j = tid + u * 512;
        unsigned dst = atomicAdd(&cursor[pc[u]], 1u);
        float x = px[u], y = py[u], z = pz[u];
        float sq = x*x + y*y + z*z;       // FROZEN: elementwise sq, seq sum
        srt[(size_t)b*NPTS + dst] = make_float4(x, y, z, sq);
        oid[(size_t)b*NPTS + dst] = (unsigned)j;
    }

    if (tid < NCELL) {                    // amin/amax final since first sync
        float* A = aabb + ((size_t)b*NCELL + tid) * 6;
        if (hist[tid] == 0) {
            A[0] = A[1] = A[2] = 1e30f;  A[3] = A[4] = A[5] = -1e30f;
        } else {
#pragma unroll
            for (int d = 0; d < 3; ++d) {
                A[d]   = unsortable_f32(amin[tid*3+d]);
                A[3+d] = unsortable_f32(amax[tid*3+d]);
            }
        }
    }
}

// ------- search: exact 11-NN over pruned cells + fused lane-parallel MLP ------
// FROZEN d2 (verified r4-r8); f64 packed keys (d2 asc, orig-j asc); tau from a
// 16-point sorted-order window bounds the true 11th d2 from above; cells kept
// iff actual-AABB min-d2 <= tau*1.0002+2e-3 (slack >> fp32 rounding ~1e-5).
__global__ __launch_bounds__(256, 4) void search_kernel(
    const float4* __restrict__ srt, const unsigned* __restrict__ oid,
    const unsigned* __restrict__ cst, const float* __restrict__ aabb,
    const float* __restrict__ pos, const float* __restrict__ vel,
    const float* __restrict__ initc,
    const float* __restrict__ W1, const float* __restrict__ b1,
    const float* __restrict__ W2, const float* __restrict__ b2,
    const float* __restrict__ W3, const float* __restrict__ b3,
    float* __restrict__ out)
{
#pragma clang fp contract(off)
    __shared__ float sA[NCELL*6];
    __shared__ unsigned sC[NCELL+1];

    int b    = blockIdx.x >> 8;           // 256 blocks per batch
    int qblk = blockIdx.x & 255;
    int tid  = threadIdx.x;
    for (int k = tid; k < NCELL*6; k += 256) sA[k] = aabb[(size_t)b*NCELL*6 + k];
    for (int k = tid; k < NCELL+1; k += 256) sC[k] = cst[(size_t)b*(NCELL+1) + k];
    __syncthreads();

    int q = tid >> 4, p = tid & 15;
    int s = qblk * QPB + q;               // this query's SORTED slot
    const float4* sp4 = srt + (size_t)b * NPTS;
    const unsigned* od = oid + (size_t)b * NPTS;

    float4 qp = sp4[s];
    float xq = qp.x, yq = qp.y, zq = qp.z, sqq = qp.w;

    // ---- tau: 11th smallest frozen-d2 over 16 sorted-order window points ----
    int wlo = s - 8; wlo = wlo < 0 ? 0 : (wlo > NPTS-16 ? NPTS-16 : wlo);
    float4 wc = sp4[wlo + p];
    float tw = xq*wc.x; tw = fmaf(yq, wc.y, tw); tw = fmaf(zq, wc.z, tw);
    float wd2 = (sqq + wc.w) - 2.0f*tw;
    unsigned vd = sortable_f32(wd2);
    unsigned tau_u = 0xFFFFFFFFu;
#pragma unroll
    for (int r = 0; r < KNN; ++r) {       // pop-one 16-lane k-way min
        unsigned h = vd, hl = (unsigned)p;
#pragma unroll
        for (int m = 1; m <= 8; m <<= 1) {
            unsigned oh = (unsigned)__shfl_xor((int)h,  m, LPQ);
            unsigned ol = (unsigned)__shfl_xor((int)hl, m, LPQ);
            bool take = (oh < h) || (oh == h && ol < hl);
            h = take ? oh : h; hl = take ? ol : hl;
        }
        tau_u = h;
        if (hl == (unsigned)p) vd = 0xFFFFFFFFu;
    }
    float tauf = unsortable_f32(tau_u);
    float tcmp = tauf * 1.0002f + 2e-3f;
    float rad  = sqrtf(fmaxf(tcmp, 0.0f)) + 1e-4f;

    int cx0 = cell_of(xq - rad), cx1 = cell_of(xq + rad);
    int cy0 = cell_of(yq - rad), cy1 = cell_of(yq + rad);
    int cz0 = cell_of(zq - rad), cz1 = cell_of(zq + rad);
    int nx = cx1-cx0+1, ny = cy1-cy0+1, nz = cz1-cz0+1;
    int total = nx * ny * nz;

    double kd[KNN];
#pragma unroll
    for (int k = 0; k < KNN; ++k) kd[k] = __longlong_as_double(SENTINEL_BITS);

    for (int e = p; e < total; e += LPQ) {
        int ex = e % nx, tmp = e / nx;
        int ey = tmp % ny, ez = tmp / ny;
        int cid = ((cz0+ez)*NC + (cy0+ey))*NC + (cx0+ex);
        const float* A = &sA[cid*6];
        float dx = fmaxf(fmaxf(A[0]-xq, 0.0f), xq-A[3]);
        float dy = fmaxf(fmaxf(A[1]-yq, 0.0f), yq-A[4]);
        float dz = fmaxf(fmaxf(A[2]-zq, 0.0f), zq-A[5]);
        float md2 = dx*dx + dy*dy + dz*dz;
        if (md2 <= tcmp) {
            unsigned ce = sC[cid+1];
            for (unsigned tt = sC[cid]; tt < ce; ++tt) {
                float4 cc = sp4[tt];
                float t = xq*cc.x;        // FROZEN d2 arithmetic
                t = fmaf(yq, cc.y, t);
                t = fmaf(zq, cc.z, t);
                float d2 = (sqq + cc.w) - 2.0f*t;
                unsigned u = sortable_f32(d2);
                unsigned lo = (u << 12) | od[tt];
                unsigned hi = 0x43300000u | (u >> 20);
                double key = __longlong_as_double(
                    ((long long)(int)hi << 32) | (unsigned long long)lo);
#pragma unroll
                for (int k = KNN-1; k > 0; --k) {
                    double mn = fmin(kd[k], key);
                    kd[k] = fmax(kd[k-1], mn);
                }
                kd[0] = fmin(kd[0], key);
            }
        }
    }

    // merge 16 per-lane sorted lists (r8 verbatim) -> res[] = orig indices
    unsigned res[KNN];
#pragma unroll
    for (int r = 0; r < KNN; ++r) {
        double h = kd[0];
#pragma unroll
        for (int m = 1; m <= 8; m <<= 1)
            h = fmin(h, __shfl_xor(h, m, LPQ));
        long long hb = __double_as_longlong(h);
        res[r] = (unsigned)(hb & 0xFFF);
        bool own = (__double_as_longlong(kd[0]) == hb);
#pragma unroll
        for (int t = 0; t < KNN-1; ++t) kd[t] = own ? kd[t+1] : kd[t];
        kd[KNN-1] = own ? __longlong_as_double(SENTINEL_BITS) : kd[KNN-1];
    }

    // ---------- fused MLP, lane-parallel, BIT-IDENTICAL to r8 ----------
    const float* pbo = pos + (size_t)b * NPTS * 3;   // ORIGINAL arrays
    const float* vb  = vel + (size_t)b * NPTS * 3;

    const float* w0 = W1 + (2*p)   * 66;
    const float* w1 = W1 + (2*p+1) * 66;
    float a0 = b1[2*p], a1 = b1[2*p+1];
#pragma unroll
    for (int k = 1; k < KNN; ++k) {       // ff 0..29: relative positions
        const float* pn = pbo + 3*(int)res[k];
        float dx = pn[0] - xq, dy = pn[1] - yq, dz = pn[2] - zq;
        int ff = 3*(k-1);
        a0 = fmaf(dx, w0[ff+0], a0); a1 = fmaf(dx, w1[ff+0], a1);
        a0 = fmaf(dy, w0[ff+1], a0); a1 = fmaf(dy, w1[ff+1], a1);
        a0 = fmaf(dz, w0[ff+2], a0); a1 = fmaf(dz, w1[ff+2], a1);
    }
#pragma unroll
    for (int k = 0; k < KNN; ++k) {       // ff 30..62: velocities
        const float* vn = vb + 3*(int)res[k];
        int ff = 30 + 3*k;
        a0 = fmaf(vn[0], w0[ff+0], a0); a1 = fmaf(vn[0], w1[ff+0], a1);
        a0 = fmaf(vn[1], w0[ff+1], a0); a1 = fmaf(vn[1], w1[ff+1], a1);
        a0 = fmaf(vn[2], w0[ff+2], a0); a1 = fmaf(vn[2], w1[ff+2], a1);
    }
    float c0 = initc[b*3+0], c1 = initc[b*3+1], c2 = initc[b*3+2];
    a0 = fmaf(c0, w0[63], a0); a1 = fmaf(c0, w1[63], a1);
    a0 = fmaf(c1, w0[64], a0); a1 = fmaf(c1, w1[64], a1);
    a0 = fmaf(c2, w0[65], a0); a1 = fmaf(c2, w1[65], a1);

    float h2 = b2[p];
    const float* w2 = W2 + p * 32;
#pragma unroll
    for (int ii = 0; ii < 32; ++ii) {
        float h1v = __shfl((ii & 1) ? a1 : a0, ii >> 1, LPQ);
        h2 = fmaf(h1v, w2[ii], h2);
    }
    int o3 = p < 6 ? p : 0;
    float po = b3[o3];
    const float* w3 = W3 + o3 * 16;
#pragma unroll
    for (int ii = 0; ii < 16; ++ii) {
        float h2v = __shfl(h2, ii, LPQ);
        po = fmaf(h2v, w3[ii], po);
    }
    float resid = (p == 0) ? xq : (p == 1) ? yq : (p == 2) ? zq : 0.0f;
    po += resid;

    unsigned oq = od[s];                  // original row of this query
    if (p < 6)
        out[((size_t)b * NPTS + (size_t)oq) * 6 + p] = po;
}

extern "C" void kernel_launch(void* const* d_in, const int* in_sizes, int n_in,
                              void* d_out, int out_size, void* d_ws, size_t ws_size,
                              hipStream_t stream) {
    const float* pos   = (const float*)d_in[0];
    const float* vel   = (const float*)d_in[1];
    const float* initc = (const float*)d_in[2];
    const float* W1    = (const float*)d_in[3];
    const float* b1    = (const float*)d_in[4];
    const float* W2    = (const float*)d_in[5];
    const float* b2    = (const float*)d_in[6];
    const float* W3    = (const float*)d_in[7];
    const float* b3    = (const float*)d_in[8];
    float* out = (float*)d_out;

    float4*   srt  = (float4*)((char*)d_ws + WS_SRT);
    unsigned* oidp = (unsigned*)((char*)d_ws + WS_OID);
    unsigned* cstp = (unsigned*)((char*)d_ws + WS_CST);
    float*    aabp = (float*)((char*)d_ws + WS_AAB);

    build_kernel<<<dim3(BATCH), dim3(512), 0, stream>>>(pos, srt, oidp, cstp, aabp);
    search_kernel<<<dim3(BATCH*256), dim3(256), 0, stream>>>(
        srt, oidp, cstp, aabp, pos, vel, initc, W1, b1, W2, b2, W3, b3, out);
}

// Round 10
// 131.284 us; speedup vs baseline: 7.4991x; 7.4991x over previous
//
#include <hip/hip_runtime.h>
#include <stdint.h>

#define BATCH 4
#define NPTS 4096
#define KNN 11            // K+1 neighbors including self
#define LPQ 16            // lanes per query
#define QPB 16            // queries per block
#define CHUNK 1024        // LDS candidate chunk
#define NCHUNK (NPTS / CHUNK)     // 4
#define CPL (CHUNK / LPQ)         // 64 candidates per lane per chunk
#define BUFN 8            // per-lane qualifier buffer slots
#define SENT_BITS 0x433FFFFFFFFFFFFFll

// monotone float -> uint mapping (ascending)
__device__ __forceinline__ unsigned sortable_f32(float d) {
    unsigned b = __float_as_uint(d);
    unsigned m = (unsigned)(((int)b) >> 31) | 0x80000000u;
    return b ^ m;
}

// Fused exact 11-NN + MLP. FROZEN d2 arithmetic (verified r4-r8):
//   sq_j = fl(fl(x2)+fl(y2)) + fl(z2); dot = fma chain; d2 = fl(si+sj)-fl(2t).
// top-k ascending d2, ties -> lower index; key = double with bits
// 0x433<<52 | sortable(d2)<<12 | j  (f64 order == (d2 asc, j asc)).
// NEW: detect/insert decoupling. Gate each candidate on u <= tau (query-global
// running-11th VALUE, stale-conservative); qualifiers append to a lane-private
// LDS buffer; when any lane fills, the wave drains buffers through the f64
// insert network and recomputes tau by a non-destructive 16-lane pop-merge.
// Dropped candidates have u > tau_stale >= tau_final -> provably not top-11.
__global__ __launch_bounds__(256, 4) void fused_kernel(
    const float* __restrict__ pos, const float* __restrict__ vel,
    const float* __restrict__ initc,
    const float* __restrict__ W1, const float* __restrict__ b1,
    const float* __restrict__ W2, const float* __restrict__ b2,
    const float* __restrict__ W3, const float* __restrict__ b3,
    float* __restrict__ out)
{
#pragma clang fp contract(off)
    // skewed float4 (x,y,z,sq): idx + (idx>>6) -> 16 partitions of 64 start
    // one float4 apart; b128 lane pattern is 2-way -> free (m136)
    __shared__ float4 sp[CHUNK + LPQ];
    // slot-major lane-private buffers: buf[slot*256 + tid] -> lanes 8B apart
    // per slot -> 2-way bank aliasing -> free
    __shared__ unsigned long long buf[BUFN * 256];

    int b    = blockIdx.x >> 8;           // 256 blocks per batch
    int qblk = blockIdx.x & 255;
    int tid  = threadIdx.x;
    const float* pb = pos + (size_t)b * NPTS * 3;

    int q = tid >> 4, p = tid & 15;
    int i = qblk * QPB + q;               // query index within batch

    float xq = pb[3*i], yq = pb[3*i+1], zq = pb[3*i+2];
    float sqq = xq*xq + yq*yq + zq*zq;    // contract(off): np sum order

    double kd[KNN];
#pragma unroll
    for (int k = 0; k < KNN; ++k) kd[k] = __longlong_as_double(SENT_BITS);
    unsigned tau_u = 0xFFFFFFFFu;
    int cnt = 0;

    for (int c = 0; c < NCHUNK; ++c) {
        if (c) __syncthreads();
        for (int j = tid; j < CHUNK; j += 256) {
            int g = c * CHUNK + j;
            float x = pb[3*g], y = pb[3*g+1], z = pb[3*g+2];
            float sq = x*x + y*y + z*z;   // FROZEN staged sq
            sp[j + (j >> 6)] = make_float4(x, y, z, sq);
        }
        __syncthreads();

        int sbase = p * (CPL + 1);
        int jg    = c * CHUNK + p * CPL;
#pragma unroll 1
        for (int jl = 0; jl < CPL; ++jl) {
            float4 cc = sp[sbase + jl];
            float t = xq * cc.x;          // FROZEN d2 arithmetic
            t = fmaf(yq, cc.y, t);
            t = fmaf(zq, cc.z, t);
            float d2 = (sqq + cc.w) - 2.0f * t;
            unsigned u = sortable_f32(d2);
            if (u <= tau_u) {             // rare per lane after warmup
                unsigned jj = (unsigned)(jg + jl);
                unsigned lo = (u << 12) | jj;
                unsigned hi = 0x43300000u | (u >> 20);
                buf[cnt * 256 + tid] =
                    ((unsigned long long)hi << 32) | (unsigned long long)lo;
                ++cnt;
            }
            if (__any(cnt == BUFN)) {
                // ---------------- flush: drain + tau update ----------------
                for (int k = 0; k < BUFN; ++k) {
                    unsigned long long kb = buf[k * 256 + tid];
                    double key = (k < cnt) ? __longlong_as_double(kb)
                                           : __longlong_as_double(SENT_BITS);
#pragma unroll
                    for (int kk = KNN-1; kk > 0; --kk) {
                        double mn = fmin(kd[kk], key);
                        kd[kk] = fmax(kd[kk-1], mn);
                    }
                    kd[0] = fmin(kd[0], key);
                }
                cnt = 0;
                // tau = true running 11th: non-destructive 16-lane pop-merge
                // (lane top-11s jointly contain the global top-11-so-far)
                double tmp[KNN];
#pragma unroll
                for (int k = 0; k < KNN; ++k) tmp[k] = kd[k];
                double h = tmp[0];
#pragma unroll
                for (int r = 0; r < KNN; ++r) {
                    h = tmp[0];
#pragma unroll
                    for (int m = 1; m <= 8; m <<= 1)
                        h = fmin(h, __shfl_xor(h, m, LPQ));
                    bool own = (__double_as_longlong(tmp[0]) ==
                                __double_as_longlong(h));
#pragma unroll
                    for (int t2 = 0; t2 < KNN-1; ++t2)
                        tmp[t2] = own ? tmp[t2+1] : tmp[t2];
                    tmp[KNN-1] = own ? __longlong_as_double(SENT_BITS)
                                     : tmp[KNN-1];
                }
                tau_u = (unsigned)((unsigned long long)
                                   __double_as_longlong(h) >> 12);
            }
        }
    }

    // final drain (no tau update needed)
    for (int k = 0; k < BUFN; ++k) {
        unsigned long long kb = buf[k * 256 + tid];
        double key = (k < cnt) ? __longlong_as_double(kb)
                               : __longlong_as_double(SENT_BITS);
#pragma unroll
        for (int kk = KNN-1; kk > 0; --kk) {
            double mn = fmin(kd[kk], key);
            kd[kk] = fmax(kd[kk-1], mn);
        }
        kd[0] = fmin(kd[0], key);
    }

    // destructive 16-lane merge (r8 verbatim) -> res[] = original indices
    unsigned res[KNN];
#pragma unroll
    for (int r = 0; r < KNN; ++r) {
        double h = kd[0];
#pragma unroll
        for (int m = 1; m <= 8; m <<= 1)
            h = fmin(h, __shfl_xor(h, m, LPQ));
        long long hb = __double_as_longlong(h);
        res[r] = (unsigned)(hb & 0xFFF);
        bool own = (__double_as_longlong(kd[0]) == hb);
#pragma unroll
        for (int t = 0; t < KNN-1; ++t) kd[t] = own ? kd[t+1] : kd[t];
        kd[KNN-1] = own ? __longlong_as_double(SENT_BITS) : kd[KNN-1];
    }

    // ---------- fused MLP, lane-parallel, BIT-IDENTICAL to r8 ----------
    const float* vb = vel + (size_t)b * NPTS * 3;

    const float* w0 = W1 + (2*p)   * 66;
    const float* w1 = W1 + (2*p+1) * 66;
    float a0 = b1[2*p], a1 = b1[2*p+1];
#pragma unroll
    for (int k = 1; k < KNN; ++k) {       // ff 0..29: relative positions
        const float* pn = pb + 3*(int)res[k];
        float dx = pn[0] - xq, dy = pn[1] - yq, dz = pn[2] - zq;
        int ff = 3*(k-1);
        a0 = fmaf(dx, w0[ff+0], a0); a1 = fmaf(dx, w1[ff+0], a1);
        a0 = fmaf(dy, w0[ff+1], a0); a1 = fmaf(dy, w1[ff+1], a1);
        a0 = fmaf(dz, w0[ff+2], a0); a1 = fmaf(dz, w1[ff+2], a1);
    }
#pragma unroll
    for (int k = 0; k < KNN; ++k) {       // ff 30..62: velocities
        const float* vn = vb + 3*(int)res[k];
        int ff = 30 + 3*k;
        a0 = fmaf(vn[0], w0[ff+0], a0); a1 = fmaf(vn[0], w1[ff+0], a1);
        a0 = fmaf(vn[1], w0[ff+1], a0); a1 = fmaf(vn[1], w1[ff+1], a1);
        a0 = fmaf(vn[2], w0[ff+2], a0); a1 = fmaf(vn[2], w1[ff+2], a1);
    }
    float c0 = initc[b*3+0], c1 = initc[b*3+1], c2 = initc[b*3+2];
    a0 = fmaf(c0, w0[63], a0); a1 = fmaf(c0, w1[63], a1);
    a0 = fmaf(c1, w0[64], a0); a1 = fmaf(c1, w1[64], a1);
    a0 = fmaf(c2, w0[65], a0); a1 = fmaf(c2, w1[65], a1);

    float h2 = b2[p];
    const float* w2 = W2 + p * 32;
#pragma unroll
    for (int ii = 0; ii < 32; ++ii) {
        float h1v = __shfl((ii & 1) ? a1 : a0, ii >> 1, LPQ);
        h2 = fmaf(h1v, w2[ii], h2);
    }
    int o3 = p < 6 ? p : 0;
    float po = b3[o3];
    const float* w3 = W3 + o3 * 16;
#pragma unroll
    for (int ii = 0; ii < 16; ++ii) {
        float h2v = __shfl(h2, ii, LPQ);
        po = fmaf(h2v, w3[ii], po);
    }
    float resid = (p == 0) ? xq : (p == 1) ? yq : (p == 2) ? zq : 0.0f;
    po += resid;                           // residual on first 3 channels

    if (p < 6)
        out[((size_t)b * NPTS + (size_t)i) * 6 + p] = po;
}

extern "C" void kernel_launch(void* const* d_in, const int* in_sizes, int n_in,
                              void* d_out, int out_size, void* d_ws, size_t ws_size,
                              hipStream_t stream) {
    const float* pos   = (const float*)d_in[0];
    const float* vel   = (const float*)d_in[1];
    const float* initc = (const float*)d_in[2];
    const float* W1    = (const float*)d_in[3];
    const float* b1    = (const float*)d_in[4];
    const float* W2    = (const float*)d_in[5];
    const float* b2    = (const float*)d_in[6];
    const float* W3    = (const float*)d_in[7];
    const float* b3    = (const float*)d_in[8];
    float* out = (float*)d_out;

    fused_kernel<<<dim3(BATCH * (NPTS / QPB)), dim3(256), 0, stream>>>(
        pos, vel, initc, W1, b1, W2, b2, W3, b3, out);
}

// Round 11
// 126.495 us; speedup vs baseline: 7.7830x; 1.0379x over previous
//
#include <hip/hip_runtime.h>
#include <stdint.h>

#define BATCH 4
#define NPTS 4096
#define KNN 11            // K+1 neighbors including self
#define LPQ 16            // lanes per query
#define QPB 16            // queries per block
#define CHUNK 1024        // LDS candidate chunk
#define NCHUNK (NPTS / CHUNK)     // 4
#define CPL (CHUNK / LPQ)         // 64 candidates per lane per chunk
#define BUFN 10           // per-lane qualifier buffer slots
#define SENT_BITS 0x433FFFFFFFFFFFFFll

// monotone float -> uint mapping (ascending)
__device__ __forceinline__ unsigned sortable_f32(float d) {
    unsigned b = __float_as_uint(d);
    unsigned m = (unsigned)(((int)b) >> 31) | 0x80000000u;
    return b ^ m;
}

// Fused exact 11-NN + MLP. FROZEN d2 arithmetic (verified r4-r10):
//   sq_j = fl(fl(x2)+fl(y2)) + fl(z2); dot = fma chain; d2 = fl(si+sj)-fl(2t).
// top-k ascending d2, ties -> lower index; key = double with bits
// 0x433<<52 | sortable(d2)<<12 | j  (f64 order == (d2 asc, j asc)).
// Detect/insert decoupling (r10) + r11 fixes: 4x manual unroll (LDS latency
// hiding), f32 gate (pack only in append path), early-break drains.
__global__ __launch_bounds__(256, 4) void fused_kernel(
    const float* __restrict__ pos, const float* __restrict__ vel,
    const float* __restrict__ initc,
    const float* __restrict__ W1, const float* __restrict__ b1,
    const float* __restrict__ W2, const float* __restrict__ b2,
    const float* __restrict__ W3, const float* __restrict__ b3,
    float* __restrict__ out)
{
#pragma clang fp contract(off)
    // skewed float4 (x,y,z,sq): idx + (idx>>6) -> partitions offset by 16B
    __shared__ float4 sp[CHUNK + LPQ];
    // slot-major lane-private buffers: lanes 8B apart -> 2-way -> free
    __shared__ unsigned long long buf[BUFN * 256];

    int b    = blockIdx.x >> 8;           // 256 blocks per batch
    int qblk = blockIdx.x & 255;
    int tid  = threadIdx.x;
    const float* pb = pos + (size_t)b * NPTS * 3;

    int q = tid >> 4, p = tid & 15;
    int i = qblk * QPB + q;               // query index within batch

    float xq = pb[3*i], yq = pb[3*i+1], zq = pb[3*i+2];
    float sqq = xq*xq + yq*yq + zq*zq;    // contract(off): np sum order

    double kd[KNN];
#pragma unroll
    for (int k = 0; k < KNN; ++k) kd[k] = __longlong_as_double(SENT_BITS);
    float tau_f = __builtin_inff();       // stale-conservative gate threshold
    int cnt = 0;

    for (int c = 0; c < NCHUNK; ++c) {
        if (c) __syncthreads();
        for (int j = tid; j < CHUNK; j += 256) {
            int g = c * CHUNK + j;
            float x = pb[3*g], y = pb[3*g+1], z = pb[3*g+2];
            float sq = x*x + y*y + z*z;   // FROZEN staged sq
            sp[j + (j >> 6)] = make_float4(x, y, z, sq);
        }
        __syncthreads();

        int sbase = p * (CPL + 1);
        int jg    = c * CHUNK + p * CPL;
        for (int jl = 0; jl < CPL; jl += 4) {
            // 4 back-to-back LDS reads + 4 independent d2 chains (ILP)
            float4 c0 = sp[sbase + jl + 0];
            float4 c1 = sp[sbase + jl + 1];
            float4 c2 = sp[sbase + jl + 2];
            float4 c3 = sp[sbase + jl + 3];
            float t0 = xq*c0.x, t1 = xq*c1.x, t2 = xq*c2.x, t3 = xq*c3.x;
            t0 = fmaf(yq, c0.y, t0); t1 = fmaf(yq, c1.y, t1);
            t2 = fmaf(yq, c2.y, t2); t3 = fmaf(yq, c3.y, t3);
            t0 = fmaf(zq, c0.z, t0); t1 = fmaf(zq, c1.z, t1);
            t2 = fmaf(zq, c2.z, t2); t3 = fmaf(zq, c3.z, t3);
            float d0 = (sqq + c0.w) - 2.0f*t0;
            float d1 = (sqq + c1.w) - 2.0f*t1;
            float d2 = (sqq + c2.w) - 2.0f*t2;
            float d3 = (sqq + c3.w) - 2.0f*t3;

            // f32 gate (== u32 gate by monotonicity); pack only on accept
#pragma unroll
            for (int s = 0; s < 4; ++s) {
                float dv = s == 0 ? d0 : s == 1 ? d1 : s == 2 ? d2 : d3;
                if (dv <= tau_f) {
                    unsigned u  = sortable_f32(dv);
                    unsigned lo = (u << 12) | (unsigned)(jg + jl + s);
                    unsigned hi = 0x43300000u | (u >> 20);
                    buf[cnt * 256 + tid] =
                        ((unsigned long long)hi << 32) | (unsigned long long)lo;
                    ++cnt;
                }
            }

            if (__any(cnt > BUFN - 4)) {
                // ---- flush: drain buffers through the f64 network ----
                for (int k = 0; k < BUFN; ++k) {
                    if (!__any(cnt > k)) break;     // early out (late flushes)
                    unsigned long long kb = buf[k * 256 + tid];
                    double key = (k < cnt) ? __longlong_as_double(kb)
                                           : __longlong_as_double(SENT_BITS);
#pragma unroll
                    for (int kk = KNN-1; kk > 0; --kk) {
                        double mn = fmin(kd[kk], key);
                        kd[kk] = fmax(kd[kk-1], mn);
                    }
                    kd[0] = fmin(kd[0], key);
                }
                cnt = 0;
                // exact running tau: non-destructive 16-lane pop-merge
                double tmp[KNN];
#pragma unroll
                for (int k = 0; k < KNN; ++k) tmp[k] = kd[k];
                double h = tmp[0];
#pragma unroll
                for (int r = 0; r < KNN; ++r) {
                    h = tmp[0];
#pragma unroll
                    for (int m = 1; m <= 8; m <<= 1)
                        h = fmin(h, __shfl_xor(h, m, LPQ));
                    bool own = (__double_as_longlong(tmp[0]) ==
                                __double_as_longlong(h));
#pragma unroll
                    for (int t2 = 0; t2 < KNN-1; ++t2)
                        tmp[t2] = own ? tmp[t2+1] : tmp[t2];
                    tmp[KNN-1] = own ? __longlong_as_double(SENT_BITS)
                                     : tmp[KNN-1];
                }
                unsigned tau_u = (unsigned)((unsigned long long)
                                            __double_as_longlong(h) >> 12);
                // unsortable: real d2 keys have top bit set
                tau_f = __uint_as_float(tau_u ^ 0x80000000u);
            }
        }
    }

    // final drain
    for (int k = 0; k < BUFN; ++k) {
        if (!__any(cnt > k)) break;
        unsigned long long kb = buf[k * 256 + tid];
        double key = (k < cnt) ? __longlong_as_double(kb)
                               : __longlong_as_double(SENT_BITS);
#pragma unroll
        for (int kk = KNN-1; kk > 0; --kk) {
            double mn = fmin(kd[kk], key);
            kd[kk] = fmax(kd[kk-1], mn);
        }
        kd[0] = fmin(kd[0], key);
    }

    // destructive 16-lane merge (r8 verbatim) -> res[] = original indices
    unsigned res[KNN];
#pragma unroll
    for (int r = 0; r < KNN; ++r) {
        double h = kd[0];
#pragma unroll
        for (int m = 1; m <= 8; m <<= 1)
            h = fmin(h, __shfl_xor(h, m, LPQ));
        long long hb = __double_as_longlong(h);
        res[r] = (unsigned)(hb & 0xFFF);
        bool own = (__double_as_longlong(kd[0]) == hb);
#pragma unroll
        for (int t = 0; t < KNN-1; ++t) kd[t] = own ? kd[t+1] : kd[t];
        kd[KNN-1] = own ? __longlong_as_double(SENT_BITS) : kd[KNN-1];
    }

    // ---------- fused MLP, lane-parallel, BIT-IDENTICAL to r8 ----------
    const float* vb = vel + (size_t)b * NPTS * 3;

    const float* w0 = W1 + (2*p)   * 66;
    const float* w1 = W1 + (2*p+1) * 66;
    float a0 = b1[2*p], a1 = b1[2*p+1];
#pragma unroll
    for (int k = 1; k < KNN; ++k) {       // ff 0..29: relative positions
        const float* pn = pb + 3*(int)res[k];
        float dx = pn[0] - xq, dy = pn[1] - yq, dz = pn[2] - zq;
        int ff = 3*(k-1);
        a0 = fmaf(dx, w0[ff+0], a0); a1 = fmaf(dx, w1[ff+0], a1);
        a0 = fmaf(dy, w0[ff+1], a0); a1 = fmaf(dy, w1[ff+1], a1);
        a0 = fmaf(dz, w0[ff+2], a0); a1 = fmaf(dz, w1[ff+2], a1);
    }
#pragma unroll
    for (int k = 0; k < KNN; ++k) {       // ff 30..62: velocities
        const float* vn = vb + 3*(int)res[k];
        int ff = 30 + 3*k;
        a0 = fmaf(vn[0], w0[ff+0], a0); a1 = fmaf(vn[0], w1[ff+0], a1);
        a0 = fmaf(vn[1], w0[ff+1], a0); a1 = fmaf(vn[1], w1[ff+1], a1);
        a0 = fmaf(vn[2], w0[ff+2], a0); a1 = fmaf(vn[2], w1[ff+2], a1);
    }
    float c0i = initc[b*3+0], c1i = initc[b*3+1], c2i = initc[b*3+2];
    a0 = fmaf(c0i, w0[63], a0); a1 = fmaf(c0i, w1[63], a1);
    a0 = fmaf(c1i, w0[64], a0); a1 = fmaf(c1i, w1[64], a1);
    a0 = fmaf(c2i, w0[65], a0); a1 = fmaf(c2i, w1[65], a1);

    float h2 = b2[p];
    const float* w2 = W2 + p * 32;
#pragma unroll
    for (int ii = 0; ii < 32; ++ii) {
        float h1v = __shfl((ii & 1) ? a1 : a0, ii >> 1, LPQ);
        h2 = fmaf(h1v, w2[ii], h2);
    }
    int o3 = p < 6 ? p : 0;
    float po = b3[o3];
    const float* w3 = W3 + o3 * 16;
#pragma unroll
    for (int ii = 0; ii < 16; ++ii) {
        float h2v = __shfl(h2, ii, LPQ);
        po = fmaf(h2v, w3[ii], po);
    }
    float resid = (p == 0) ? xq : (p == 1) ? yq : (p == 2) ? zq : 0.0f;
    po += resid;                           // residual on first 3 channels

    if (p < 6)
        out[((size_t)b * NPTS + (size_t)i) * 6 + p] = po;
}

extern "C" void kernel_launch(void* const* d_in, const int* in_sizes, int n_in,
                              void* d_out, int out_size, void* d_ws, size_t ws_size,
                              hipStream_t stream) {
    const float* pos   = (const float*)d_in[0];
    const float* vel   = (const float*)d_in[1];
    const float* initc = (const float*)d_in[2];
    const float* W1    = (const float*)d_in[3];
    const float* b1    = (const float*)d_in[4];
    const float* W2    = (const float*)d_in[5];
    const float* b2    = (const float*)d_in[6];
    const float* W3    = (const float*)d_in[7];
    const float* b3    = (const float*)d_in[8];
    float* out = (float*)d_out;

    fused_kernel<<<dim3(BATCH * (NPTS / QPB)), dim3(256), 0, stream>>>(
        pos, vel, initc, W1, b1, W2, b2, W3, b3, out);
}